// Round 1
// baseline (63.519 us; speedup 1.0000x reference)
//
#include <hip/hip_runtime.h>
#include <stdint.h>

// StringLabelEncoder: x [N_ROWS, 8] int32 rows, classes_table [N_CLASSES, 8] int32.
// For each row, output the index of the (unique) matching class row, int32.
//
// Strategy: hash join. Build an open-addressing hash table (class-row hash ->
// class index) in d_ws, then each row hashes its 8 words and linear-probes,
// verifying candidates with a full 8-word compare against the (L2-resident)
// class table. O(1) probes/row instead of O(C) brute force.

#define N_ROWS    100000
#define N_CLASSES 1000
#define N_WORDS   8
#define TBL_SIZE  4096          // power of two, ~25% load factor
#define TBL_MASK  (TBL_SIZE - 1)

__device__ __forceinline__ uint32_t hash8(int4 a, int4 b) {
    uint64_t h = 0x9E3779B97F4A7C15ull;
    uint32_t w[8] = {(uint32_t)a.x, (uint32_t)a.y, (uint32_t)a.z, (uint32_t)a.w,
                     (uint32_t)b.x, (uint32_t)b.y, (uint32_t)b.z, (uint32_t)b.w};
#pragma unroll
    for (int i = 0; i < 8; ++i) {
        h ^= w[i];
        h *= 0x100000001B3ull;   // FNV-1a style mix
    }
    h ^= h >> 33;
    h *= 0xFF51AFD7ED558CCDull;
    h ^= h >> 33;
    return (uint32_t)h;
}

__global__ void build_table_kernel(const int* __restrict__ tab,
                                   int* __restrict__ ht) {
    int c = blockIdx.x * blockDim.x + threadIdx.x;
    if (c >= N_CLASSES) return;
    const int4* t4 = (const int4*)(tab + (size_t)c * N_WORDS);
    int4 a = t4[0];
    int4 b = t4[1];
    uint32_t h = hash8(a, b) & TBL_MASK;
    // Linear probe insert; slots initialized to -1 (empty).
    while (atomicCAS(&ht[h], -1, c) != -1) {
        h = (h + 1) & TBL_MASK;
    }
}

__global__ void encode_kernel(const int* __restrict__ x,
                              const int* __restrict__ tab,
                              const int* __restrict__ ht,
                              int* __restrict__ out) {
    int r = blockIdx.x * blockDim.x + threadIdx.x;
    if (r >= N_ROWS) return;
    const int4* x4 = (const int4*)(x + (size_t)r * N_WORDS);
    int4 a = x4[0];
    int4 b = x4[1];
    uint32_t h = hash8(a, b) & TBL_MASK;
    int res = 0;
    while (true) {
        int c = ht[h];
        if (c < 0) { res = 0; break; }  // not found (shouldn't happen: every row is a known label)
        const int4* t4 = (const int4*)(tab + (size_t)c * N_WORDS);
        int4 ta = t4[0];
        int4 tb = t4[1];
        if (ta.x == a.x && ta.y == a.y && ta.z == a.z && ta.w == a.w &&
            tb.x == b.x && tb.y == b.y && tb.z == b.z && tb.w == b.w) {
            res = c;
            break;
        }
        h = (h + 1) & TBL_MASK;
    }
    out[r] = res;
}

extern "C" void kernel_launch(void* const* d_in, const int* in_sizes, int n_in,
                              void* d_out, int out_size, void* d_ws, size_t ws_size,
                              hipStream_t stream) {
    const int* x   = (const int*)d_in[0];   // [N_ROWS, 8]
    const int* tab = (const int*)d_in[1];   // [N_CLASSES, 8]
    int* out = (int*)d_out;                 // [N_ROWS] int32
    int* ht  = (int*)d_ws;                  // TBL_SIZE int32 hash table

    // ws is re-poisoned to 0xAA before every call — reset table to -1 (empty).
    hipMemsetAsync(ht, 0xFF, TBL_SIZE * sizeof(int), stream);

    build_table_kernel<<<(N_CLASSES + 255) / 256, 256, 0, stream>>>(tab, ht);
    encode_kernel<<<(N_ROWS + 255) / 256, 256, 0, stream>>>(x, tab, ht, out);
}

// Round 2
// 61.165 us; speedup vs baseline: 1.0385x; 1.0385x over previous
//
#include <hip/hip_runtime.h>
#include <stdint.h>

// StringLabelEncoder: x [N_ROWS, 8] int32, classes_table [N_CLASSES, 8] int32.
// Output: index of the (unique) matching class row per input row, int32.
//
// Single fused kernel: each block builds a private LDS hash table (4096 slots,
// 16 KB) plus an LDS copy of the class table (32 KB), then encodes its chunk
// of rows entirely from LDS. One dispatch, no workspace, no cross-block deps.

#define N_ROWS    100000
#define N_CLASSES 1000
#define N_WORDS   8
#define TBL_SIZE  4096          // power of two, ~25% load factor
#define TBL_MASK  (TBL_SIZE - 1)
#define BLOCK     256
#define ROWS_PER_THREAD 2
#define ROWS_PER_BLOCK  (BLOCK * ROWS_PER_THREAD)   // 512
#define NBLOCKS   ((N_ROWS + ROWS_PER_BLOCK - 1) / ROWS_PER_BLOCK)  // 196

__device__ __forceinline__ uint32_t hash8(int4 a, int4 b) {
    uint64_t h = 0x9E3779B97F4A7C15ull;
    uint32_t w[8] = {(uint32_t)a.x, (uint32_t)a.y, (uint32_t)a.z, (uint32_t)a.w,
                     (uint32_t)b.x, (uint32_t)b.y, (uint32_t)b.z, (uint32_t)b.w};
#pragma unroll
    for (int i = 0; i < 8; ++i) {
        h ^= w[i];
        h *= 0x100000001B3ull;   // FNV-1a style mix
    }
    h ^= h >> 33;
    h *= 0xFF51AFD7ED558CCDull;
    h ^= h >> 33;
    return (uint32_t)h;
}

__global__ __launch_bounds__(BLOCK) void encode_fused(
        const int* __restrict__ x,
        const int* __restrict__ tab,
        int* __restrict__ out) {
    __shared__ int ht[TBL_SIZE];                  // 16 KB: hash slot -> class idx
    __shared__ int ctab[N_CLASSES * N_WORDS];     // 32 KB: class table copy

    const int t = threadIdx.x;

    // Phase 1: clear hash table.
#pragma unroll
    for (int i = t; i < TBL_SIZE; i += BLOCK) ht[i] = -1;
    __syncthreads();

    // Phase 2: stage class table into LDS + insert into LDS hash table.
    for (int c = t; c < N_CLASSES; c += BLOCK) {
        const int4* t4 = (const int4*)(tab + (size_t)c * N_WORDS);
        int4 a = t4[0];
        int4 b = t4[1];
        ((int4*)ctab)[c * 2]     = a;
        ((int4*)ctab)[c * 2 + 1] = b;
        uint32_t h = hash8(a, b) & TBL_MASK;
        while (atomicCAS(&ht[h], -1, c) != -1) h = (h + 1) & TBL_MASK;
    }
    __syncthreads();

    // Phase 3: encode this block's rows from LDS.
    const int base = blockIdx.x * ROWS_PER_BLOCK + t;
#pragma unroll
    for (int i = 0; i < ROWS_PER_THREAD; ++i) {
        int r = base + i * BLOCK;
        if (r >= N_ROWS) continue;
        const int4* x4 = (const int4*)(x + (size_t)r * N_WORDS);
        int4 a = x4[0];
        int4 b = x4[1];
        uint32_t h = hash8(a, b) & TBL_MASK;
        int res = 0;
        while (true) {
            int c = ht[h];
            if (c < 0) { res = 0; break; }   // unreachable: every row is a known label
            int4 ta = ((const int4*)ctab)[c * 2];
            int4 tb = ((const int4*)ctab)[c * 2 + 1];
            if (ta.x == a.x && ta.y == a.y && ta.z == a.z && ta.w == a.w &&
                tb.x == b.x && tb.y == b.y && tb.z == b.z && tb.w == b.w) {
                res = c;
                break;
            }
            h = (h + 1) & TBL_MASK;
        }
        out[r] = res;
    }
}

extern "C" void kernel_launch(void* const* d_in, const int* in_sizes, int n_in,
                              void* d_out, int out_size, void* d_ws, size_t ws_size,
                              hipStream_t stream) {
    const int* x   = (const int*)d_in[0];   // [N_ROWS, 8]
    const int* tab = (const int*)d_in[1];   // [N_CLASSES, 8]
    int* out = (int*)d_out;                 // [N_ROWS] int32

    encode_fused<<<NBLOCKS, BLOCK, 0, stream>>>(x, tab, out);
}

// Round 3
// 60.169 us; speedup vs baseline: 1.0557x; 1.0165x over previous
//
#include <hip/hip_runtime.h>
#include <stdint.h>

// StringLabelEncoder: x [N_ROWS, 8] int32, classes_table [N_CLASSES, 8] int32.
// Output: index of the (unique) matching class row per input row, int32.
//
// Single fused kernel. Each block builds a private 4096-slot LDS hash table
// keyed on a multiply-shift of word 0 (inputs are uniform random int32, so
// word 0 alone is a perfect-quality hash; full-row verify vs the L2-resident
// class table resolves any collision). Each thread's input row is loaded
// BEFORE the table build so HBM latency hides under the insert phase.

#define N_ROWS    100000
#define N_CLASSES 1000
#define N_WORDS   8
#define TBL_SIZE  4096
#define TBL_MASK  (TBL_SIZE - 1)
#define BLOCK     256
#define NBLOCKS   ((N_ROWS + BLOCK - 1) / BLOCK)   // 391

__device__ __forceinline__ uint32_t hslot(uint32_t w0) {
    // Fibonacci multiply-shift: 2 VALU ops, uniform for random keys.
    return (w0 * 2654435761u) >> (32 - 12);   // 12 = log2(TBL_SIZE)
}

__global__ __launch_bounds__(BLOCK) void encode_fused(
        const int* __restrict__ x,
        const int* __restrict__ tab,
        int* __restrict__ out) {
    __shared__ int ht[TBL_SIZE];   // 16 KB: slot -> class idx (-1 empty)

    const int t = threadIdx.x;
    const int r = blockIdx.x * BLOCK + t;
    const bool valid = (r < N_ROWS);

    // Issue my row's global loads now; latency hides under the table build.
    int4 a = {0, 0, 0, 0}, b = {0, 0, 0, 0};
    if (valid) {
        const int4* x4 = (const int4*)(x + (size_t)r * N_WORDS);
        a = x4[0];
        b = x4[1];
    }

    // Phase 1: clear hash table (16 slots/thread).
#pragma unroll
    for (int i = t; i < TBL_SIZE; i += BLOCK) ht[i] = -1;
    __syncthreads();

    // Phase 2: insert all classes (word-0 key only; ~4 classes/thread).
    for (int c = t; c < N_CLASSES; c += BLOCK) {
        uint32_t h = hslot((uint32_t)tab[(size_t)c * N_WORDS]) & TBL_MASK;
        while (atomicCAS(&ht[h], -1, c) != -1) h = (h + 1) & TBL_MASK;
    }
    __syncthreads();

    if (!valid) return;

    // Phase 3: probe + verify against L2-resident global table.
    uint32_t h = hslot((uint32_t)a.x) & TBL_MASK;
    int res = 0;
    while (true) {
        int c = ht[h];
        if (c < 0) break;   // unreachable: every row is a known label
        const int4* t4 = (const int4*)(tab + (size_t)c * N_WORDS);
        int4 ta = t4[0];
        int4 tb = t4[1];
        if (ta.x == a.x && ta.y == a.y && ta.z == a.z && ta.w == a.w &&
            tb.x == b.x && tb.y == b.y && tb.z == b.z && tb.w == b.w) {
            res = c;
            break;
        }
        h = (h + 1) & TBL_MASK;
    }
    out[r] = res;
}

extern "C" void kernel_launch(void* const* d_in, const int* in_sizes, int n_in,
                              void* d_out, int out_size, void* d_ws, size_t ws_size,
                              hipStream_t stream) {
    const int* x   = (const int*)d_in[0];   // [N_ROWS, 8]
    const int* tab = (const int*)d_in[1];   // [N_CLASSES, 8]
    int* out = (int*)d_out;                 // [N_ROWS] int32

    encode_fused<<<NBLOCKS, BLOCK, 0, stream>>>(x, tab, out);
}